// Round 6
// baseline (206.370 us; speedup 1.0000x reference)
//
#include <hip/hip_runtime.h>
#include <cstdint>

typedef short bf16x8 __attribute__((ext_vector_type(8)));
typedef float f32x4 __attribute__((ext_vector_type(4)));

#define MFMA16(a, b, c) __builtin_amdgcn_mfma_f32_16x16x32_bf16((a), (b), (c), 0, 0, 0)

// async global->LDS DMA, 16B per lane. LDS dest is wave-uniform base + lane*16.
__device__ __forceinline__ void gl16(const unsigned short* g, unsigned short* l) {
  __builtin_amdgcn_global_load_lds(
      (const __attribute__((address_space(1))) unsigned int*)g,
      (__attribute__((address_space(3))) unsigned int*)l, 16, 0, 0);
}

__device__ __forceinline__ unsigned short f2b(float f) {
  union { float f; unsigned int u; } x; x.f = f;
  unsigned int r = x.u + 0x7fffu + ((x.u >> 16) & 1u);
  return (unsigned short)(r >> 16);
}

// fast pack two fp32 -> packed bf16x2 (round half-up; fine for probs in [1,16])
__device__ __forceinline__ unsigned int pack2(float lo, float hi) {
  union { float f; unsigned int u; } a, b;
  a.f = lo; b.f = hi;
  return ((a.u + 0x8000u) >> 16) | ((b.u + 0x8000u) & 0xffff0000u);
}

#define NB 2
#define NS 2048
#define ND 768
#define NH 12
#define DHD 64
#define MTOK 4096  // NB*NS

// ws element offsets (ushort/bf16 elements)
#define OFF_XB 0
#define OFF_WB 3145728   // 5 x 589824 converted weights
#define OFF_QK 6094848   // 4 x 3145728 : Qr,Qi,Kr,Ki  [4096][768]
#define OFF_VT 18677760  // Vt [2][12][64][2048]

__global__ void cvt_kernel(const float* __restrict__ src,
                           unsigned short* __restrict__ dst, int n4, float scale) {
  int i = blockIdx.x * blockDim.x + threadIdx.x;
  if (i >= n4) return;
  float4 v = ((const float4*)src)[i];
  ushort4 o;
  o.x = f2b(v.x * scale); o.y = f2b(v.y * scale);
  o.z = f2b(v.z * scale); o.w = f2b(v.w * scale);
  ((ushort4*)dst)[i] = o;
}

// all 5 weight matrices in one launch
__global__ void wcvt_kernel(const float* __restrict__ s0, const float* __restrict__ s1,
                            const float* __restrict__ s2, const float* __restrict__ s3,
                            const float* __restrict__ s4, unsigned short* __restrict__ dst,
                            float qs) {
  const int bz = blockIdx.x / 576;           // 576 blocks per weight (147456/256)
  const int i = (blockIdx.x % 576) * 256 + threadIdx.x;
  const float* src = bz == 0 ? s0 : bz == 1 ? s1 : bz == 2 ? s2 : bz == 3 ? s3 : s4;
  const float scale = bz < 2 ? qs : 1.0f;    // Wqr, Wqi carry the exp2-domain scale
  float4 v = ((const float4*)src)[i];
  ushort4 o;
  o.x = f2b(v.x * scale); o.y = f2b(v.y * scale);
  o.z = f2b(v.z * scale); o.w = f2b(v.w * scale);
  ((ushort4*)(dst + bz * 589824))[i] = o;
}

// out = X @ W^T for 5 weights (z). z<4 -> row-major bf16 [4096][768];
// z==4 -> V transposed per head: Vt[b][h][dh][s].
// BK=32 full double-buffer: staging = 32 KB (X dbuf + W dbuf), total LDS
// 34.8 KB -> 4 blocks/CU and the ENTIRE 960-block grid co-resident.
// 2-phase: stage(kk+1) issued before compute(kk), one barrier per step.
// XOR swizzle over 4 chunks/row: LDS[r][c] = G[r][c ^ (r&3)], applied on the
// global source chunk and the ds_read offset (both-sides rule #21).
// XCD-chunked block swizzle. Coalesced LDS-staged epilogue.
__global__ __launch_bounds__(256) void proj_kernel(
    const unsigned short* __restrict__ Xb, const unsigned short* __restrict__ Wb,
    unsigned short* __restrict__ QK, unsigned short* __restrict__ Vt) {
  __shared__ __align__(16) unsigned short S[17408];  // 34816 B; staging uses first 32 KB
  // Xbuf: S[0..4095], S[4096..8191];  Wbuf: S[8192..12287], S[12288..16383]

  // swizzled block decode: lin -> sb so each XCD gets 120 consecutive sb
  const int lin = blockIdx.x + 6 * (blockIdx.y + 5 * blockIdx.z);
  const int sb = (lin & 7) * 120 + (lin >> 3);
  const int n0 = (sb % 6) * 128;
  const int rem = sb / 6;
  const int z = rem % 5;
  const int m0 = (rem / 5) * 128;

  const unsigned short* Wz = Wb + z * 589824;
  const int tid = threadIdx.x;
  const int lane = tid & 63;
  const int w = tid >> 6;
  const int wm = (w >> 1) * 64;
  const int wn = (w & 1) * 64;
  const int col = lane & 15, quad = lane >> 4;

  // staging: wave w covers rows [w*32, w*32+32) in 2 gl16 of 16 rows each.
  // lane l -> row lr = l>>2 within the 16-row group, chunk l&3; source chunk
  // pre-swizzled: lc = (l&3) ^ (lr&3).
  const int lr = lane >> 2;
  const int lc = (lane & 3) ^ (lr & 3);
  const unsigned short* gX = Xb + (m0 + w * 32 + lr) * ND + lc * 8;
  const unsigned short* gW = Wz + (n0 + w * 32 + lr) * ND + lc * 8;
  const int stg = (w * 32) * 32;  // wave's row-block offset within a buffer (ushorts)

  f32x4 acc[4][4] = {};

  // prologue: stage K-step 0 into buf 0
  gl16(gX, S + stg);
  gl16(gX + 16 * ND, S + stg + 512);
  gl16(gW, S + 8192 + stg);
  gl16(gW + 16 * ND, S + 8192 + stg + 512);
  __syncthreads();  // drain: buf0 visible

  int cur = 0;
  const int foA = (quad ^ (col & 3)) * 8;  // swizzled chunk offset for ds_read
  for (int kk = 0; kk < 24; kk++) {
    if (kk < 23) {  // issue next-step loads BEFORE compute
      const int k0n = (kk + 1) * 32;
      unsigned short* dX = S + ((cur ^ 1) * 4096) + stg;
      unsigned short* dW = S + 8192 + ((cur ^ 1) * 4096) + stg;
      gl16(gX + k0n, dX);
      gl16(gX + 16 * ND + k0n, dX + 512);
      gl16(gW + k0n, dW);
      gl16(gW + 16 * ND + k0n, dW + 512);
    }
    const unsigned short* Xc = S + cur * 4096;
    const unsigned short* Wc = S + 8192 + cur * 4096;
    bf16x8 af[4], bw[4];
#pragma unroll
    for (int t = 0; t < 4; t++) {
      af[t] = *(const bf16x8*)(Xc + (wm + t * 16 + col) * 32 + foA);
      bw[t] = *(const bf16x8*)(Wc + (wn + t * 16 + col) * 32 + foA);
    }
    __builtin_amdgcn_s_setprio(1);
#pragma unroll
    for (int mt = 0; mt < 4; mt++)
#pragma unroll
      for (int nt = 0; nt < 4; nt++)
        acc[mt][nt] = MFMA16(af[mt], bw[nt], acc[mt][nt]);
    __builtin_amdgcn_s_setprio(0);
    __syncthreads();  // drains vmcnt(0): next buf ready; cur safe to overwrite
    cur ^= 1;
  }

  // ---- epilogue: LDS-staged coalesced writeout (reuses S as T[128][136]) ----
  unsigned short* T = S;

  if (z < 4) {
#pragma unroll
    for (int mt = 0; mt < 4; mt++) {
      int rl = wm + mt * 16 + quad * 4;
#pragma unroll
      for (int nt = 0; nt < 4; nt++) {
        int cl = wn + nt * 16 + col;
#pragma unroll
        for (int r = 0; r < 4; r++) T[(rl + r) * 136 + cl] = f2b(acc[mt][nt][r]);
      }
    }
    __syncthreads();
    unsigned short* out = QK + z * (MTOK * ND);
    const int rr = tid >> 4;
    const int cc = (tid & 15) * 8;
#pragma unroll
    for (int p = 0; p < 8; p++) {
      int row = p * 16 + rr;
      uint4 v = *(const uint4*)(T + row * 136 + cc);
      *(uint4*)(out + (m0 + row) * ND + n0 + cc) = v;
    }
  } else {
    // transpose in LDS: T[dh_local][s_local], so global write is contiguous in s
#pragma unroll
    for (int mt = 0; mt < 4; mt++) {
      int rl = wm + mt * 16 + quad * 4;  // token index (s_local), multiple of 4
#pragma unroll
      for (int nt = 0; nt < 4; nt++) {
        int cl = wn + nt * 16 + col;  // dh_local
        ushort4 pk;
        pk.x = f2b(acc[mt][nt][0]);
        pk.y = f2b(acc[mt][nt][1]);
        pk.z = f2b(acc[mt][nt][2]);
        pk.w = f2b(acc[mt][nt][3]);
        *(ushort4*)(T + cl * 136 + rl) = pk;
      }
    }
    __syncthreads();
    const int rr = tid >> 4;
    const int cc = (tid & 15) * 8;
    const int b = m0 >> 11;
    const int s_base = m0 & 2047;
#pragma unroll
    for (int p = 0; p < 8; p++) {
      int dhl = p * 16 + rr;
      int c = n0 + dhl;
      int h = c >> 6, dh = c & 63;
      uint4 v = *(const uint4*)(T + dhl * 136 + cc);
      *(uint4*)(Vt + (((b * NH + h) * DHD + dh) * NS + s_base + cc)) = v;
    }
  }
}

// Flash attention, scores transposed (S^T = K Q^T), complex magnitude variant.
// No online max (scores bounded; exp2 domain folded into Q scale).
// V double-buffered; V(t+1) issued at the TOP barrier (its target buffer holds
// V(t-1), dead since PV(t-1) completed before this barrier) so it is covered
// by the whole tile; K/Ki staged at the mid barrier (covered by PV phase).
// T5 setprio around both MFMA clusters (3 independently-phased blocks/CU).
// XCD-chunked swizzle keeps K/V panels resident in one XCD's L2.
__global__ __launch_bounds__(256) void attn_kernel(
    const unsigned short* __restrict__ QK, const unsigned short* __restrict__ Vt,
    float* __restrict__ outp) {
  __shared__ __align__(16) unsigned short Krs[4096];
  __shared__ __align__(16) unsigned short Kis[4096];
  __shared__ __align__(16) unsigned short Vts[8192];  // [2][64][64] double-buffered
  __shared__ __align__(16) unsigned short Ps[4096];

  const int lin = blockIdx.x + 32 * (blockIdx.y + 12 * blockIdx.z);
  const int sb = (lin & 7) * 96 + (lin >> 3);
  const int qt = sb & 31;
  const int h = (sb >> 5) % 12;
  const int b = sb / 384;
  const int tid = threadIdx.x, lane = tid & 63, w = tid >> 6;
  const int col = lane & 15, quad = lane >> 4;
  const int c7 = col & 7;
  const int jb = quad ^ c7;
  const int f0 = jb * 8, f1 = (jb ^ 4) * 8;  // swizzled fragment offsets (ushorts)

  const unsigned short* Qr = QK;
  const unsigned short* Qi = QK + MTOK * ND;
  const unsigned short* Krp = QK + 2 * MTOK * ND;
  const unsigned short* Kip = QK + 3 * MTOK * ND;

  const int q_tok = b * NS + qt * 64 + w * 16 + col;
  const int qoff = q_tok * ND + h * DHD;

  // Q as B-fragments: B[k=d][n=q], lane holds 8 consecutive d at its q.
  bf16x8 qrf[2], qif[2], qrn[2];
#pragma unroll
  for (int kk = 0; kk < 2; kk++) {
    qrf[kk] = *(const bf16x8*)(Qr + qoff + kk * 32 + quad * 8);
    qif[kk] = *(const bf16x8*)(Qi + qoff + kk * 32 + quad * 8);
    qrn[kk] = qrf[kk] ^ (short)0x8000;  // -Qr (bf16 sign flip)
  }

  // staging: wave w stages rows [w*8, w*8+8) and [32+w*8, ...) of each array.
  const int lr = lane >> 3;
  const int lc = (lane & 7) ^ (lr & 7);
  const unsigned short* gKr = Krp + (b * NS + w * 8 + lr) * ND + h * DHD + lc * 8;
  const unsigned short* gKi = Kip + (b * NS + w * 8 + lr) * ND + h * DHD + lc * 8;
  const unsigned short* gV = Vt + (b * NH + h) * (DHD * NS) + (w * 8 + lr) * NS + lc * 8;
  const int st = (w * 8) * 64;  // wave-uniform LDS base offset within a buffer

  unsigned short* PsW = Ps + w * 1024;

  f32x4 o[4] = {};  // O^T tiles: rows d = dt*16+quad*4+r, col q
  float lrow = 0.f;

  // prologue: stage tile 0 (K/Ki single buffer; V into buf 0)
  gl16(gKr, Krs + st);
  gl16(gKr + 32 * ND, Krs + st + 2048);
  gl16(gKi, Kis + st);
  gl16(gKi + 32 * ND, Kis + st + 2048);
  gl16(gV, Vts + st);
  gl16(gV + 32 * NS, Vts + st + 2048);
  gKr += 64 * ND;
  gKi += 64 * ND;
  gV += 64;

  int vb = 0;
  for (int kt = 0; kt < 32; kt++) {
    __syncthreads();  // drains vmcnt(0): tile kt's K/Ki/V landed

    // V(t+1) early-issue: Vts[vb^1] holds V(t-1), dead since PV(t-1) (pre-barrier)
    if (kt < 31) {
      const int nb = (vb ^ 1) * 4096;
      gl16(gV, Vts + nb + st);
      gl16(gV + 32 * NS, Vts + nb + st + 2048);
      gV += 64;
    }

    // ---- QK^T phase (reads Krs/Kis; writes P to LDS) ----
#pragma unroll
    for (int mt = 0; mt < 4; mt++) {
      f32x4 sr = {}, si = {};
      const int rowb = (mt * 16 + col) * 64;
      bf16x8 kr0 = *(const bf16x8*)(Krs + rowb + f0);
      bf16x8 ki0 = *(const bf16x8*)(Kis + rowb + f0);
      bf16x8 kr1 = *(const bf16x8*)(Krs + rowb + f1);
      bf16x8 ki1 = *(const bf16x8*)(Kis + rowb + f1);
      __builtin_amdgcn_s_setprio(1);
      sr = MFMA16(kr0, qrf[0], sr);
      sr = MFMA16(ki0, qif[0], sr);
      si = MFMA16(kr0, qif[0], si);
      si = MFMA16(ki0, qrn[0], si);
      sr = MFMA16(kr1, qrf[1], sr);
      sr = MFMA16(ki1, qif[1], sr);
      si = MFMA16(kr1, qif[1], si);
      si = MFMA16(ki1, qrn[1], si);
      __builtin_amdgcn_s_setprio(0);

      float e0, e1, e2, e3;
      {
        float m0f = __builtin_amdgcn_sqrtf(sr[0] * sr[0] + si[0] * si[0]);
        float m1f = __builtin_amdgcn_sqrtf(sr[1] * sr[1] + si[1] * si[1]);
        float m2f = __builtin_amdgcn_sqrtf(sr[2] * sr[2] + si[2] * si[2]);
        float m3f = __builtin_amdgcn_sqrtf(sr[3] * sr[3] + si[3] * si[3]);
        e0 = __builtin_amdgcn_exp2f(m0f);
        e1 = __builtin_amdgcn_exp2f(m1f);
        e2 = __builtin_amdgcn_exp2f(m2f);
        e3 = __builtin_amdgcn_exp2f(m3f);
      }
      lrow += (e0 + e1) + (e2 + e3);
      uint2 pk;
      pk.x = pack2(e0, e1);
      pk.y = pack2(e2, e3);
      *(uint2*)(PsW + col * 64 + (((mt * 2 + (quad >> 1)) ^ c7) * 8) + (quad & 1) * 4) = pk;
    }

    __syncthreads();  // all waves done reading Krs/Kis (K dead); lgkm drained -> Ps visible

    // ---- stage K/Ki of tile kt+1: latency hides under the PV phase below ----
    if (kt < 31) {
      gl16(gKr, Krs + st);
      gl16(gKr + 32 * ND, Krs + st + 2048);
      gl16(gKi, Kis + st);
      gl16(gKi + 32 * ND, Kis + st + 2048);
      gKr += 64 * ND;
      gKi += 64 * ND;
    }

    // ---- PV phase: O^T += V^T · P^T (reads Vts[vb], Ps) ----
    const unsigned short* Vc = Vts + vb * 4096;
    bf16x8 pb0 = *(const bf16x8*)(PsW + col * 64 + f0);
    bf16x8 pb1 = *(const bf16x8*)(PsW + col * 64 + f1);
    __builtin_amdgcn_s_setprio(1);
#pragma unroll
    for (int dt = 0; dt < 4; dt++) {
      const int rowv = (dt * 16 + col) * 64;
      bf16x8 va0 = *(const bf16x8*)(Vc + rowv + f0);
      bf16x8 va1 = *(const bf16x8*)(Vc + rowv + f1);
      o[dt] = MFMA16(va0, pb0, o[dt]);
      o[dt] = MFMA16(va1, pb1, o[dt]);
    }
    __builtin_amdgcn_s_setprio(0);
    vb ^= 1;
  }

  lrow += __shfl_xor(lrow, 16);
  lrow += __shfl_xor(lrow, 32);
  float inv_l = 1.0f / lrow;
  float* op = outp + (size_t)q_tok * ND + h * DHD;
#pragma unroll
  for (int dt = 0; dt < 4; dt++) {
    float4 v;
    v.x = o[dt][0] * inv_l;
    v.y = o[dt][1] * inv_l;
    v.z = o[dt][2] * inv_l;
    v.w = o[dt][3] * inv_l;
    *(float4*)(op + dt * 16 + quad * 4) = v;
  }
}

extern "C" void kernel_launch(void* const* d_in, const int* in_sizes, int n_in,
                              void* d_out, int out_size, void* d_ws, size_t ws_size,
                              hipStream_t stream) {
  const float* X = (const float*)d_in[0];
  unsigned short* ws = (unsigned short*)d_ws;
  unsigned short* Xb = ws + OFF_XB;
  unsigned short* Wb = ws + OFF_WB;
  unsigned short* QK = ws + OFF_QK;
  unsigned short* Vt = ws + OFF_VT;

  // scale = 1/sqrt(Dh) * log2(e), folded into Wq so scores come out in exp2 domain
  const float QSCALE = 0.125f * 1.44269504088896f;

  cvt_kernel<<<3072, 256, 0, stream>>>(X, Xb, 786432, 1.0f);
  wcvt_kernel<<<2880, 256, 0, stream>>>((const float*)d_in[1], (const float*)d_in[2],
                                        (const float*)d_in[3], (const float*)d_in[4],
                                        (const float*)d_in[5], Wb, QSCALE);

  proj_kernel<<<dim3(6, 5, 32), 256, 0, stream>>>(Xb, Wb, QK, Vt);
  attn_kernel<<<dim3(32, 12, 2), 256, 0, stream>>>(QK, Vt, (float*)d_out);
}

// Round 8
// 192.708 us; speedup vs baseline: 1.0709x; 1.0709x over previous
//
#include <hip/hip_runtime.h>
#include <cstdint>

typedef short bf16x8 __attribute__((ext_vector_type(8)));
typedef float f32x4 __attribute__((ext_vector_type(4)));

#define MFMA16(a, b, c) __builtin_amdgcn_mfma_f32_16x16x32_bf16((a), (b), (c), 0, 0, 0)

// async global->LDS DMA, 16B per lane. LDS dest is wave-uniform base + lane*16.
__device__ __forceinline__ void gl16(const unsigned short* g, unsigned short* l) {
  __builtin_amdgcn_global_load_lds(
      (const __attribute__((address_space(1))) unsigned int*)g,
      (__attribute__((address_space(3))) unsigned int*)l, 16, 0, 0);
}

__device__ __forceinline__ unsigned short f2b(float f) {
  union { float f; unsigned int u; } x; x.f = f;
  unsigned int r = x.u + 0x7fffu + ((x.u >> 16) & 1u);
  return (unsigned short)(r >> 16);
}

// fast pack two fp32 -> packed bf16x2 (round half-up; fine for probs in [1,16])
__device__ __forceinline__ unsigned int pack2(float lo, float hi) {
  union { float f; unsigned int u; } a, b;
  a.f = lo; b.f = hi;
  return ((a.u + 0x8000u) >> 16) | ((b.u + 0x8000u) & 0xffff0000u);
}

#define NB 2
#define NS 2048
#define ND 768
#define NH 12
#define DHD 64
#define MTOK 4096  // NB*NS

// ws element offsets (ushort/bf16 elements)
#define OFF_XB 0
#define OFF_WB 3145728   // 5 x 589824 converted weights
#define OFF_QK 6094848   // 4 x 3145728 : Qr,Qi,Kr,Ki  [4096][768]
#define OFF_VT 18677760  // Vt [2][12][64][2048]

__global__ void cvt_kernel(const float* __restrict__ src,
                           unsigned short* __restrict__ dst, int n4, float scale) {
  int i = blockIdx.x * blockDim.x + threadIdx.x;
  if (i >= n4) return;
  float4 v = ((const float4*)src)[i];
  ushort4 o;
  o.x = f2b(v.x * scale); o.y = f2b(v.y * scale);
  o.z = f2b(v.z * scale); o.w = f2b(v.w * scale);
  ((ushort4*)dst)[i] = o;
}

// all 5 weight matrices in one launch
__global__ void wcvt_kernel(const float* __restrict__ s0, const float* __restrict__ s1,
                            const float* __restrict__ s2, const float* __restrict__ s3,
                            const float* __restrict__ s4, unsigned short* __restrict__ dst,
                            float qs) {
  const int bz = blockIdx.x / 576;           // 576 blocks per weight (147456/256)
  const int i = (blockIdx.x % 576) * 256 + threadIdx.x;
  const float* src = bz == 0 ? s0 : bz == 1 ? s1 : bz == 2 ? s2 : bz == 3 ? s3 : s4;
  const float scale = bz < 2 ? qs : 1.0f;    // Wqr, Wqi carry the exp2-domain scale
  float4 v = ((const float4*)src)[i];
  ushort4 o;
  o.x = f2b(v.x * scale); o.y = f2b(v.y * scale);
  o.z = f2b(v.z * scale); o.w = f2b(v.w * scale);
  ((ushort4*)(dst + bz * 589824))[i] = o;
}

// out = X @ W^T for 5 weights (z). z<4 -> row-major bf16 [4096][768];
// z==4 -> V transposed per head: Vt[b][h][dh][s].
// ROUND-5 VERSION (best measured): BK=64, 2-phase double-buffered staging,
// no setprio. XOR swizzle on global source chunk + ds_read offset (rule #21).
// XCD-chunked block swizzle. Coalesced LDS-staged epilogue.
__global__ __launch_bounds__(256) void proj_kernel(
    const unsigned short* __restrict__ Xb, const unsigned short* __restrict__ Wb,
    unsigned short* __restrict__ QK, unsigned short* __restrict__ Vt) {
  __shared__ __align__(16) unsigned short S[32768];  // 64 KB: X dbuf | W dbuf; epi reuses front

  // swizzled block decode: lin -> sb so each XCD gets 120 consecutive sb
  const int lin = blockIdx.x + 6 * (blockIdx.y + 5 * blockIdx.z);
  const int sb = (lin & 7) * 120 + (lin >> 3);
  const int n0 = (sb % 6) * 128;
  const int rem = sb / 6;
  const int z = rem % 5;
  const int m0 = (rem / 5) * 128;

  const unsigned short* Wz = Wb + z * 589824;
  const int tid = threadIdx.x;
  const int lane = tid & 63;
  const int w = tid >> 6;
  const int wm = (w >> 1) * 64;
  const int wn = (w & 1) * 64;
  const int col = lane & 15, quad = lane >> 4;
  const int c7 = col & 7;

  // staging geometry: wave w covers rows [w*32, w*32+32) in 4 instrs of 8 rows
  const int lr = lane >> 3;                    // row within 8-row group
  const int lc = (lane & 7) ^ (lr & 7);        // pre-swizzled source chunk
  const unsigned short* gX = Xb + (m0 + w * 32 + lr) * ND + lc * 8;
  const unsigned short* gW = Wz + (n0 + w * 32 + lr) * ND + lc * 8;
  unsigned short* lX = S + (w * 32) * 64;              // wave-uniform LDS bases (buf 0)
  unsigned short* lW = S + 16384 + (w * 32) * 64;

  f32x4 acc[4][4] = {};

  // prologue: stage K-step 0 into buf 0
#pragma unroll
  for (int i = 0; i < 4; i++) {
    gl16(gX + i * (8 * ND), lX + i * 512);
    gl16(gW + i * (8 * ND), lW + i * 512);
  }
  __syncthreads();  // drain: buf0 visible

  int cur = 0;
  for (int kk = 0; kk < 12; kk++) {
    if (kk < 11) {  // issue next-tile loads BEFORE compute (latency hides under MFMAs)
      const int k0n = (kk + 1) * 64;
      unsigned short* dX = lX + ((cur ^ 1) * 8192);
      unsigned short* dW = lW + ((cur ^ 1) * 8192);
#pragma unroll
      for (int i = 0; i < 4; i++) {
        gl16(gX + i * (8 * ND) + k0n, dX + i * 512);
        gl16(gW + i * (8 * ND) + k0n, dW + i * 512);
      }
    }
    const unsigned short* Xc = S + cur * 8192;
    const unsigned short* Wc = S + 16384 + cur * 8192;
#pragma unroll
    for (int ks = 0; ks < 2; ks++) {
      bf16x8 af[4], bw[4];
#pragma unroll
      for (int t = 0; t < 4; t++) {
        const int fo = (((ks * 4 + quad) ^ c7) * 8);
        af[t] = *(const bf16x8*)(Xc + (wm + t * 16 + col) * 64 + fo);
        bw[t] = *(const bf16x8*)(Wc + (wn + t * 16 + col) * 64 + fo);
      }
#pragma unroll
      for (int mt = 0; mt < 4; mt++)
#pragma unroll
        for (int nt = 0; nt < 4; nt++)
          acc[mt][nt] = MFMA16(af[mt], bw[nt], acc[mt][nt]);
    }
    __syncthreads();  // drains vmcnt(0): next buf ready; cur safe to overwrite
    cur ^= 1;
  }

  // ---- epilogue: LDS-staged coalesced writeout (reuses S front as T[128][136]) ----
  unsigned short* T = S;

  if (z < 4) {
#pragma unroll
    for (int mt = 0; mt < 4; mt++) {
      int rl = wm + mt * 16 + quad * 4;
#pragma unroll
      for (int nt = 0; nt < 4; nt++) {
        int cl = wn + nt * 16 + col;
#pragma unroll
        for (int r = 0; r < 4; r++) T[(rl + r) * 136 + cl] = f2b(acc[mt][nt][r]);
      }
    }
    __syncthreads();
    unsigned short* out = QK + z * (MTOK * ND);
    const int rr = tid >> 4;
    const int cc = (tid & 15) * 8;
#pragma unroll
    for (int p = 0; p < 8; p++) {
      int row = p * 16 + rr;
      uint4 v = *(const uint4*)(T + row * 136 + cc);
      *(uint4*)(out + (m0 + row) * ND + n0 + cc) = v;
    }
  } else {
    // transpose in LDS: T[dh_local][s_local], so global write is contiguous in s
#pragma unroll
    for (int mt = 0; mt < 4; mt++) {
      int rl = wm + mt * 16 + quad * 4;  // token index (s_local), multiple of 4
#pragma unroll
      for (int nt = 0; nt < 4; nt++) {
        int cl = wn + nt * 16 + col;  // dh_local
        ushort4 pk;
        pk.x = f2b(acc[mt][nt][0]);
        pk.y = f2b(acc[mt][nt][1]);
        pk.z = f2b(acc[mt][nt][2]);
        pk.w = f2b(acc[mt][nt][3]);
        *(ushort4*)(T + cl * 136 + rl) = pk;
      }
    }
    __syncthreads();
    const int rr = tid >> 4;
    const int cc = (tid & 15) * 8;
    const int b = m0 >> 11;
    const int s_base = m0 & 2047;
#pragma unroll
    for (int p = 0; p < 8; p++) {
      int dhl = p * 16 + rr;
      int c = n0 + dhl;
      int h = c >> 6, dh = c & 63;
      uint4 v = *(const uint4*)(T + dhl * 136 + cc);
      *(uint4*)(Vt + (((b * NH + h) * DHD + dh) * NS + s_base + cc)) = v;
    }
  }
}

// Flash attention, scores transposed (S^T = K Q^T), complex magnitude variant.
// No online max (scores bounded; exp2 domain folded into Q scale).
//
// Single-barrier full double-buffer: P stays in REGISTERS (no Ps LDS).
// The PV B-fragment is a fixed lane permutation of the QK C-fragment:
// dest lane (col,quad) needs P[k=quad*8+j][q=col]; source lanes are
// col+32*(quad&1) and +16, at mt = quad>>1 (pb0) / 2+(quad>>1) (pb1).
// 4 __shfl + conditional keep per mt replace the LDS pack/store/load and
// the mid-tile barrier. LDS = K,Ki,V all x2 = 48 KB -> 3 blocks/CU; all 6
// loads for tile t+1 issue right after the (single) barrier, covered by
// the ENTIRE tile-t compute (~1500+ cy >> HBM latency).
// XCD-chunked swizzle keeps K/V panels resident in one XCD's L2.
__global__ __launch_bounds__(256) void attn_kernel(
    const unsigned short* __restrict__ QK, const unsigned short* __restrict__ Vt,
    float* __restrict__ outp) {
  __shared__ __align__(16) unsigned short Krs[8192];  // [2][64][64]
  __shared__ __align__(16) unsigned short Kis[8192];
  __shared__ __align__(16) unsigned short Vts[8192];

  const int lin = blockIdx.x + 32 * (blockIdx.y + 12 * blockIdx.z);
  const int sb = (lin & 7) * 96 + (lin >> 3);
  const int qt = sb & 31;
  const int h = (sb >> 5) % 12;
  const int b = sb / 384;
  const int tid = threadIdx.x, lane = tid & 63, w = tid >> 6;
  const int col = lane & 15, quad = lane >> 4;
  const int c7 = col & 7;
  const int jb = quad ^ c7;
  const int f0 = jb * 8, f1 = (jb ^ 4) * 8;  // swizzled fragment offsets (ushorts)

  const unsigned short* Qr = QK;
  const unsigned short* Qi = QK + MTOK * ND;
  const unsigned short* Krp = QK + 2 * MTOK * ND;
  const unsigned short* Kip = QK + 3 * MTOK * ND;

  const int q_tok = b * NS + qt * 64 + w * 16 + col;
  const int qoff = q_tok * ND + h * DHD;

  // Q as B-fragments: B[k=d][n=q], lane holds 8 consecutive d at its q.
  bf16x8 qrf[2], qif[2], qrn[2];
#pragma unroll
  for (int kk = 0; kk < 2; kk++) {
    qrf[kk] = *(const bf16x8*)(Qr + qoff + kk * 32 + quad * 8);
    qif[kk] = *(const bf16x8*)(Qi + qoff + kk * 32 + quad * 8);
    qrn[kk] = qrf[kk] ^ (short)0x8000;  // -Qr (bf16 sign flip)
  }

  // staging: wave w stages rows [w*8, w*8+8) and [32+w*8, ...) of each array.
  const int lr = lane >> 3;
  const int lc = (lane & 7) ^ (lr & 7);
  const unsigned short* gKr = Krp + (b * NS + w * 8 + lr) * ND + h * DHD + lc * 8;
  const unsigned short* gKi = Kip + (b * NS + w * 8 + lr) * ND + h * DHD + lc * 8;
  const unsigned short* gV = Vt + (b * NH + h) * (DHD * NS) + (w * 8 + lr) * NS + lc * 8;
  const int st = (w * 8) * 64;  // wave-uniform LDS base offset within a buffer

  // P-shuffle source lanes (constant per thread)
  const int srcA = col + ((quad & 1) << 5);
  const int srcB = srcA + 16;
  const int hi = quad >> 1;  // which mt of a pair this lane keeps

  f32x4 o[4] = {};  // O^T tiles: rows d = dt*16+quad*4+r, col q
  float lrow = 0.f;

  // prologue: stage tile 0 into buf 0
  gl16(gKr, Krs + st);
  gl16(gKr + 32 * ND, Krs + st + 2048);
  gl16(gKi, Kis + st);
  gl16(gKi + 32 * ND, Kis + st + 2048);
  gl16(gV, Vts + st);
  gl16(gV + 32 * NS, Vts + st + 2048);
  gKr += 64 * ND;
  gKi += 64 * ND;
  gV += 64;

  int cur = 0;
  for (int kt = 0; kt < 32; kt++) {
    __syncthreads();  // drains vmcnt(0): tile kt landed; alt buffers (kt-1) dead

    // stage tile kt+1 into alt buffers; covered by ALL of tile kt's compute
    if (kt < 31) {
      const int nb = (cur ^ 1) * 4096;
      gl16(gKr, Krs + nb + st);
      gl16(gKr + 32 * ND, Krs + nb + st + 2048);
      gl16(gKi, Kis + nb + st);
      gl16(gKi + 32 * ND, Kis + nb + st + 2048);
      gl16(gV, Vts + nb + st);
      gl16(gV + 32 * NS, Vts + nb + st + 2048);
      gKr += 64 * ND;
      gKi += 64 * ND;
      gV += 64;
    }

    const unsigned short* Kc = Krs + cur * 4096;
    const unsigned short* Ic = Kis + cur * 4096;
    const unsigned short* Vc = Vts + cur * 4096;

    // ---- QK^T + softmax + P redistribution (all in registers) ----
    unsigned int pb00 = 0, pb01 = 0, pb02 = 0, pb03 = 0;
    unsigned int pb10 = 0, pb11 = 0, pb12 = 0, pb13 = 0;
#pragma unroll
    for (int mt = 0; mt < 4; mt++) {
      f32x4 sr = {}, si = {};
      const int rowb = (mt * 16 + col) * 64;
      bf16x8 kr0 = *(const bf16x8*)(Kc + rowb + f0);
      bf16x8 ki0 = *(const bf16x8*)(Ic + rowb + f0);
      bf16x8 kr1 = *(const bf16x8*)(Kc + rowb + f1);
      bf16x8 ki1 = *(const bf16x8*)(Ic + rowb + f1);
      sr = MFMA16(kr0, qrf[0], sr);
      sr = MFMA16(ki0, qif[0], sr);
      si = MFMA16(kr0, qif[0], si);
      si = MFMA16(ki0, qrn[0], si);
      sr = MFMA16(kr1, qrf[1], sr);
      sr = MFMA16(ki1, qif[1], sr);
      si = MFMA16(kr1, qif[1], si);
      si = MFMA16(ki1, qrn[1], si);

      float e0, e1, e2, e3;
      {
        float m0f = __builtin_amdgcn_sqrtf(sr[0] * sr[0] + si[0] * si[0]);
        float m1f = __builtin_amdgcn_sqrtf(sr[1] * sr[1] + si[1] * si[1]);
        float m2f = __builtin_amdgcn_sqrtf(sr[2] * sr[2] + si[2] * si[2]);
        float m3f = __builtin_amdgcn_sqrtf(sr[3] * sr[3] + si[3] * si[3]);
        e0 = __builtin_amdgcn_exp2f(m0f);
        e1 = __builtin_amdgcn_exp2f(m1f);
        e2 = __builtin_amdgcn_exp2f(m2f);
        e3 = __builtin_amdgcn_exp2f(m3f);
      }
      lrow += (e0 + e1) + (e2 + e3);
      unsigned int pk0 = pack2(e0, e1);
      unsigned int pk1 = pack2(e2, e3);
      // redistribute: this lane's PV B-frag dwords live in lanes srcA/srcB
      unsigned int a0 = __shfl(pk0, srcA);
      unsigned int a1 = __shfl(pk1, srcA);
      unsigned int b0 = __shfl(pk0, srcB);
      unsigned int b1 = __shfl(pk1, srcB);
      if (mt == 0) {
        pb00 = a0; pb01 = a1; pb02 = b0; pb03 = b1;
      } else if (mt == 1) {
        if (hi) { pb00 = a0; pb01 = a1; pb02 = b0; pb03 = b1; }
      } else if (mt == 2) {
        pb10 = a0; pb11 = a1; pb12 = b0; pb13 = b1;
      } else {
        if (hi) { pb10 = a0; pb11 = a1; pb12 = b0; pb13 = b1; }
      }
    }

    union { unsigned int u[4]; bf16x8 v; } U0, U1;
    U0.u[0] = pb00; U0.u[1] = pb01; U0.u[2] = pb02; U0.u[3] = pb03;
    U1.u[0] = pb10; U1.u[1] = pb11; U1.u[2] = pb12; U1.u[3] = pb13;
    bf16x8 pb0 = U0.v;
    bf16x8 pb1 = U1.v;

    // ---- PV phase: O^T += V^T · P^T ----
#pragma unroll
    for (int dt = 0; dt < 4; dt++) {
      const int rowv = (dt * 16 + col) * 64;
      bf16x8 va0 = *(const bf16x8*)(Vc + rowv + f0);
      bf16x8 va1 = *(const bf16x8*)(Vc + rowv + f1);
      o[dt] = MFMA16(va0, pb0, o[dt]);
      o[dt] = MFMA16(va1, pb1, o[dt]);
    }
    cur ^= 1;
  }

  lrow += __shfl_xor(lrow, 16);
  lrow += __shfl_xor(lrow, 32);
  float inv_l = 1.0f / lrow;
  float* op = outp + (size_t)q_tok * ND + h * DHD;
#pragma unroll
  for (int dt = 0; dt < 4; dt++) {
    float4 v;
    v.x = o[dt][0] * inv_l;
    v.y = o[dt][1] * inv_l;
    v.z = o[dt][2] * inv_l;
    v.w = o[dt][3] * inv_l;
    *(float4*)(op + dt * 16 + quad * 4) = v;
  }
}

extern "C" void kernel_launch(void* const* d_in, const int* in_sizes, int n_in,
                              void* d_out, int out_size, void* d_ws, size_t ws_size,
                              hipStream_t stream) {
  const float* X = (const float*)d_in[0];
  unsigned short* ws = (unsigned short*)d_ws;
  unsigned short* Xb = ws + OFF_XB;
  unsigned short* Wb = ws + OFF_WB;
  unsigned short* QK = ws + OFF_QK;
  unsigned short* Vt = ws + OFF_VT;

  // scale = 1/sqrt(Dh) * log2(e), folded into Wq so scores come out in exp2 domain
  const float QSCALE = 0.125f * 1.44269504088896f;

  cvt_kernel<<<3072, 256, 0, stream>>>(X, Xb, 786432, 1.0f);
  wcvt_kernel<<<2880, 256, 0, stream>>>((const float*)d_in[1], (const float*)d_in[2],
                                        (const float*)d_in[3], (const float*)d_in[4],
                                        (const float*)d_in[5], Wb, QSCALE);

  proj_kernel<<<dim3(6, 5, 32), 256, 0, stream>>>(Xb, Wb, QK, Vt);
  attn_kernel<<<dim3(32, 12, 2), 256, 0, stream>>>(QK, Vt, (float*)d_out);
}

// Round 9
// 188.575 us; speedup vs baseline: 1.0944x; 1.0219x over previous
//
#include <hip/hip_runtime.h>
#include <cstdint>

typedef short bf16x8 __attribute__((ext_vector_type(8)));
typedef float f32x4 __attribute__((ext_vector_type(4)));

#define MFMA16(a, b, c) __builtin_amdgcn_mfma_f32_16x16x32_bf16((a), (b), (c), 0, 0, 0)

// async global->LDS DMA, 16B per lane. LDS dest is wave-uniform base + lane*16.
__device__ __forceinline__ void gl16(const unsigned short* g, unsigned short* l) {
  __builtin_amdgcn_global_load_lds(
      (const __attribute__((address_space(1))) unsigned int*)g,
      (__attribute__((address_space(3))) unsigned int*)l, 16, 0, 0);
}

__device__ __forceinline__ unsigned short f2b(float f) {
  union { float f; unsigned int u; } x; x.f = f;
  unsigned int r = x.u + 0x7fffu + ((x.u >> 16) & 1u);
  return (unsigned short)(r >> 16);
}

// fast pack two fp32 -> packed bf16x2 (round half-up; fine for probs in [1,16])
__device__ __forceinline__ unsigned int pack2(float lo, float hi) {
  union { float f; unsigned int u; } a, b;
  a.f = lo; b.f = hi;
  return ((a.u + 0x8000u) >> 16) | ((b.u + 0x8000u) & 0xffff0000u);
}

#define NB 2
#define NS 2048
#define ND 768
#define NH 12
#define DHD 64
#define MTOK 4096  // NB*NS

// ws element offsets (ushort/bf16 elements)
#define OFF_XB 0
#define OFF_WB 3145728   // 5 x 589824 converted weights
#define OFF_QK 6094848   // 4 x 3145728 : Qr,Qi,Kr,Ki  [4096][768]
#define OFF_VT 18677760  // Vt [2][12][64][2048]

__global__ void cvt_kernel(const float* __restrict__ src,
                           unsigned short* __restrict__ dst, int n4, float scale) {
  int i = blockIdx.x * blockDim.x + threadIdx.x;
  if (i >= n4) return;
  float4 v = ((const float4*)src)[i];
  ushort4 o;
  o.x = f2b(v.x * scale); o.y = f2b(v.y * scale);
  o.z = f2b(v.z * scale); o.w = f2b(v.w * scale);
  ((ushort4*)dst)[i] = o;
}

// all 5 weight matrices in one launch
__global__ void wcvt_kernel(const float* __restrict__ s0, const float* __restrict__ s1,
                            const float* __restrict__ s2, const float* __restrict__ s3,
                            const float* __restrict__ s4, unsigned short* __restrict__ dst,
                            float qs) {
  const int bz = blockIdx.x / 576;           // 576 blocks per weight (147456/256)
  const int i = (blockIdx.x % 576) * 256 + threadIdx.x;
  const float* src = bz == 0 ? s0 : bz == 1 ? s1 : bz == 2 ? s2 : bz == 3 ? s3 : s4;
  const float scale = bz < 2 ? qs : 1.0f;    // Wqr, Wqi carry the exp2-domain scale
  float4 v = ((const float4*)src)[i];
  ushort4 o;
  o.x = f2b(v.x * scale); o.y = f2b(v.y * scale);
  o.z = f2b(v.z * scale); o.w = f2b(v.w * scale);
  ((ushort4*)(dst + bz * 589824))[i] = o;
}

// out = X @ W^T for 5 weights (z). z<4 -> row-major bf16 [4096][768];
// z==4 -> V transposed per head: Vt[b][h][dh][s].
// BK=64, 2-phase double-buffered staging (round-5 structure).
// XOR swizzle on global source chunk + ds_read offset (rule #21).
// Z-MAJOR XCD decode: each XCD's 120-block chunk spans ONE z (its W panel
// = 1.125 MB, L2-resident) and ~20 X panels (~3.75 MB) -> staged reads feed
// from L2 instead of thrashing 5.6 MB of W per XCD (the old m-major decode).
__global__ __launch_bounds__(256) void proj_kernel(
    const unsigned short* __restrict__ Xb, const unsigned short* __restrict__ Wb,
    unsigned short* __restrict__ QK, unsigned short* __restrict__ Vt) {
  __shared__ __align__(16) unsigned short S[32768];  // 64 KB: X dbuf | W dbuf; epi reuses front

  // swizzled block decode: lin -> sb so each XCD gets 120 consecutive sb;
  // sb decoded (z major, then m, then n): W stays L2-resident per XCD.
  const int lin = blockIdx.x + 6 * (blockIdx.y + 5 * blockIdx.z);
  const int sb = (lin & 7) * 120 + (lin >> 3);
  const int n0 = (sb % 6) * 128;
  const int m0 = ((sb / 6) % 32) * 128;
  const int z = sb / 192;

  const unsigned short* Wz = Wb + z * 589824;
  const int tid = threadIdx.x;
  const int lane = tid & 63;
  const int w = tid >> 6;
  const int wm = (w >> 1) * 64;
  const int wn = (w & 1) * 64;
  const int col = lane & 15, quad = lane >> 4;
  const int c7 = col & 7;

  // staging geometry: wave w covers rows [w*32, w*32+32) in 4 instrs of 8 rows
  const int lr = lane >> 3;                    // row within 8-row group
  const int lc = (lane & 7) ^ (lr & 7);        // pre-swizzled source chunk
  const unsigned short* gX = Xb + (m0 + w * 32 + lr) * ND + lc * 8;
  const unsigned short* gW = Wz + (n0 + w * 32 + lr) * ND + lc * 8;
  unsigned short* lX = S + (w * 32) * 64;              // wave-uniform LDS bases (buf 0)
  unsigned short* lW = S + 16384 + (w * 32) * 64;

  f32x4 acc[4][4] = {};

  // prologue: stage K-step 0 into buf 0
#pragma unroll
  for (int i = 0; i < 4; i++) {
    gl16(gX + i * (8 * ND), lX + i * 512);
    gl16(gW + i * (8 * ND), lW + i * 512);
  }
  __syncthreads();  // drain: buf0 visible

  int cur = 0;
  for (int kk = 0; kk < 12; kk++) {
    if (kk < 11) {  // issue next-tile loads BEFORE compute (latency hides under MFMAs)
      const int k0n = (kk + 1) * 64;
      unsigned short* dX = lX + ((cur ^ 1) * 8192);
      unsigned short* dW = lW + ((cur ^ 1) * 8192);
#pragma unroll
      for (int i = 0; i < 4; i++) {
        gl16(gX + i * (8 * ND) + k0n, dX + i * 512);
        gl16(gW + i * (8 * ND) + k0n, dW + i * 512);
      }
    }
    const unsigned short* Xc = S + cur * 8192;
    const unsigned short* Wc = S + 16384 + cur * 8192;
#pragma unroll
    for (int ks = 0; ks < 2; ks++) {
      bf16x8 af[4], bw[4];
#pragma unroll
      for (int t = 0; t < 4; t++) {
        const int fo = (((ks * 4 + quad) ^ c7) * 8);
        af[t] = *(const bf16x8*)(Xc + (wm + t * 16 + col) * 64 + fo);
        bw[t] = *(const bf16x8*)(Wc + (wn + t * 16 + col) * 64 + fo);
      }
#pragma unroll
      for (int mt = 0; mt < 4; mt++)
#pragma unroll
        for (int nt = 0; nt < 4; nt++)
          acc[mt][nt] = MFMA16(af[mt], bw[nt], acc[mt][nt]);
    }
    __syncthreads();  // drains vmcnt(0): next buf ready; cur safe to overwrite
    cur ^= 1;
  }

  // ---- epilogue: LDS-staged coalesced writeout (reuses S front as T[128][136]) ----
  unsigned short* T = S;

  if (z < 4) {
#pragma unroll
    for (int mt = 0; mt < 4; mt++) {
      int rl = wm + mt * 16 + quad * 4;
#pragma unroll
      for (int nt = 0; nt < 4; nt++) {
        int cl = wn + nt * 16 + col;
#pragma unroll
        for (int r = 0; r < 4; r++) T[(rl + r) * 136 + cl] = f2b(acc[mt][nt][r]);
      }
    }
    __syncthreads();
    unsigned short* out = QK + z * (MTOK * ND);
    const int rr = tid >> 4;
    const int cc = (tid & 15) * 8;
#pragma unroll
    for (int p = 0; p < 8; p++) {
      int row = p * 16 + rr;
      uint4 v = *(const uint4*)(T + row * 136 + cc);
      *(uint4*)(out + (m0 + row) * ND + n0 + cc) = v;
    }
  } else {
    // transpose in LDS: T[dh_local][s_local], so global write is contiguous in s
#pragma unroll
    for (int mt = 0; mt < 4; mt++) {
      int rl = wm + mt * 16 + quad * 4;  // token index (s_local), multiple of 4
#pragma unroll
      for (int nt = 0; nt < 4; nt++) {
        int cl = wn + nt * 16 + col;  // dh_local
        ushort4 pk;
        pk.x = f2b(acc[mt][nt][0]);
        pk.y = f2b(acc[mt][nt][1]);
        pk.z = f2b(acc[mt][nt][2]);
        pk.w = f2b(acc[mt][nt][3]);
        *(ushort4*)(T + cl * 136 + rl) = pk;
      }
    }
    __syncthreads();
    const int rr = tid >> 4;
    const int cc = (tid & 15) * 8;
    const int b = m0 >> 11;
    const int s_base = m0 & 2047;
#pragma unroll
    for (int p = 0; p < 8; p++) {
      int dhl = p * 16 + rr;
      int c = n0 + dhl;
      int h = c >> 6, dh = c & 63;
      uint4 v = *(const uint4*)(T + dhl * 136 + cc);
      *(uint4*)(Vt + (((b * NH + h) * DHD + dh) * NS + s_base + cc)) = v;
    }
  }
}

// Flash attention, scores transposed (S^T = K Q^T), complex magnitude variant.
// ROUND-5 VERSION (best measured 94.8 us): V-only double-buffer, Ps in LDS,
// K/Ki staged at mid barrier (covered by PV), V(t+1) into alt buffer.
// Load scheduling proven ~invariant (r3/r5/r8 all ~95); this is the cheapest.
// XCD-chunked swizzle keeps K/V panels resident in one XCD's L2.
__global__ __launch_bounds__(256) void attn_kernel(
    const unsigned short* __restrict__ QK, const unsigned short* __restrict__ Vt,
    float* __restrict__ outp) {
  __shared__ __align__(16) unsigned short Krs[4096];
  __shared__ __align__(16) unsigned short Kis[4096];
  __shared__ __align__(16) unsigned short Vts[8192];  // [2][64][64] double-buffered
  __shared__ __align__(16) unsigned short Ps[4096];

  const int lin = blockIdx.x + 32 * (blockIdx.y + 12 * blockIdx.z);
  const int sb = (lin & 7) * 96 + (lin >> 3);
  const int qt = sb & 31;
  const int h = (sb >> 5) % 12;
  const int b = sb / 384;
  const int tid = threadIdx.x, lane = tid & 63, w = tid >> 6;
  const int col = lane & 15, quad = lane >> 4;
  const int c7 = col & 7;
  const int jb = quad ^ c7;
  const int f0 = jb * 8, f1 = (jb ^ 4) * 8;  // swizzled fragment offsets (ushorts)

  const unsigned short* Qr = QK;
  const unsigned short* Qi = QK + MTOK * ND;
  const unsigned short* Krp = QK + 2 * MTOK * ND;
  const unsigned short* Kip = QK + 3 * MTOK * ND;

  const int q_tok = b * NS + qt * 64 + w * 16 + col;
  const int qoff = q_tok * ND + h * DHD;

  // Q as B-fragments: B[k=d][n=q], lane holds 8 consecutive d at its q.
  bf16x8 qrf[2], qif[2], qrn[2];
#pragma unroll
  for (int kk = 0; kk < 2; kk++) {
    qrf[kk] = *(const bf16x8*)(Qr + qoff + kk * 32 + quad * 8);
    qif[kk] = *(const bf16x8*)(Qi + qoff + kk * 32 + quad * 8);
    qrn[kk] = qrf[kk] ^ (short)0x8000;  // -Qr (bf16 sign flip)
  }

  // staging: wave w stages rows [w*8, w*8+8) and [32+w*8, ...) of each array.
  const int lr = lane >> 3;
  const int lc = (lane & 7) ^ (lr & 7);
  const unsigned short* gKr = Krp + (b * NS + w * 8 + lr) * ND + h * DHD + lc * 8;
  const unsigned short* gKi = Kip + (b * NS + w * 8 + lr) * ND + h * DHD + lc * 8;
  const unsigned short* gV = Vt + (b * NH + h) * (DHD * NS) + (w * 8 + lr) * NS + lc * 8;
  const int st = (w * 8) * 64;  // wave-uniform LDS base offset within a buffer

  unsigned short* PsW = Ps + w * 1024;

  f32x4 o[4] = {};  // O^T tiles: rows d = dt*16+quad*4+r, col q
  float lrow = 0.f;

  // prologue: stage tile 0 (K/Ki single buffer; V into buf 0)
  gl16(gKr, Krs + st);
  gl16(gKr + 32 * ND, Krs + st + 2048);
  gl16(gKi, Kis + st);
  gl16(gKi + 32 * ND, Kis + st + 2048);
  gl16(gV, Vts + st);
  gl16(gV + 32 * NS, Vts + st + 2048);
  gKr += 64 * ND;
  gKi += 64 * ND;
  gV += 64;

  int vb = 0;
  for (int kt = 0; kt < 32; kt++) {
    __syncthreads();  // drains vmcnt(0): tile kt's K/Ki/V landed

    // ---- QK^T phase (reads Krs/Kis; writes P to LDS) ----
#pragma unroll
    for (int mt = 0; mt < 4; mt++) {
      f32x4 sr = {}, si = {};
      const int rowb = (mt * 16 + col) * 64;
      bf16x8 kr0 = *(const bf16x8*)(Krs + rowb + f0);
      bf16x8 ki0 = *(const bf16x8*)(Kis + rowb + f0);
      bf16x8 kr1 = *(const bf16x8*)(Krs + rowb + f1);
      bf16x8 ki1 = *(const bf16x8*)(Kis + rowb + f1);
      sr = MFMA16(kr0, qrf[0], sr);
      sr = MFMA16(ki0, qif[0], sr);
      si = MFMA16(kr0, qif[0], si);
      si = MFMA16(ki0, qrn[0], si);
      sr = MFMA16(kr1, qrf[1], sr);
      sr = MFMA16(ki1, qif[1], sr);
      si = MFMA16(kr1, qif[1], si);
      si = MFMA16(ki1, qrn[1], si);

      float e0, e1, e2, e3;
      {
        float m0f = __builtin_amdgcn_sqrtf(sr[0] * sr[0] + si[0] * si[0]);
        float m1f = __builtin_amdgcn_sqrtf(sr[1] * sr[1] + si[1] * si[1]);
        float m2f = __builtin_amdgcn_sqrtf(sr[2] * sr[2] + si[2] * si[2]);
        float m3f = __builtin_amdgcn_sqrtf(sr[3] * sr[3] + si[3] * si[3]);
        e0 = __builtin_amdgcn_exp2f(m0f);
        e1 = __builtin_amdgcn_exp2f(m1f);
        e2 = __builtin_amdgcn_exp2f(m2f);
        e3 = __builtin_amdgcn_exp2f(m3f);
      }
      lrow += (e0 + e1) + (e2 + e3);
      uint2 pk;
      pk.x = pack2(e0, e1);
      pk.y = pack2(e2, e3);
      *(uint2*)(PsW + col * 64 + (((mt * 2 + (quad >> 1)) ^ c7) * 8) + (quad & 1) * 4) = pk;
    }

    __syncthreads();  // all waves done reading Krs/Kis (K dead); lgkm drained -> Ps visible

    // ---- stage tile kt+1 NOW: latency hides under the PV phase below ----
    if (kt < 31) {
      const int nb = (vb ^ 1) * 4096;
      gl16(gKr, Krs + st);
      gl16(gKr + 32 * ND, Krs + st + 2048);
      gl16(gKi, Kis + st);
      gl16(gKi + 32 * ND, Kis + st + 2048);
      gl16(gV, Vts + nb + st);
      gl16(gV + 32 * NS, Vts + nb + st + 2048);
      gKr += 64 * ND;
      gKi += 64 * ND;
      gV += 64;
    }

    // ---- PV phase: O^T += V^T · P^T (reads Vts[vb], Ps) ----
    const unsigned short* Vc = Vts + vb * 4096;
    bf16x8 pb0 = *(const bf16x8*)(PsW + col * 64 + f0);
    bf16x8 pb1 = *(const bf16x8*)(PsW + col * 64 + f1);
#pragma unroll
    for (int dt = 0; dt < 4; dt++) {
      const int rowv = (dt * 16 + col) * 64;
      bf16x8 va0 = *(const bf16x8*)(Vts + vb * 4096 + rowv + f0);
      bf16x8 va1 = *(const bf16x8*)(Vc + rowv + f1);
      o[dt] = MFMA16(va0, pb0, o[dt]);
      o[dt] = MFMA16(va1, pb1, o[dt]);
    }
    vb ^= 1;
  }

  lrow += __shfl_xor(lrow, 16);
  lrow += __shfl_xor(lrow, 32);
  float inv_l = 1.0f / lrow;
  float* op = outp + (size_t)q_tok * ND + h * DHD;
#pragma unroll
  for (int dt = 0; dt < 4; dt++) {
    float4 v;
    v.x = o[dt][0] * inv_l;
    v.y = o[dt][1] * inv_l;
    v.z = o[dt][2] * inv_l;
    v.w = o[dt][3] * inv_l;
    *(float4*)(op + dt * 16 + quad * 4) = v;
  }
}

extern "C" void kernel_launch(void* const* d_in, const int* in_sizes, int n_in,
                              void* d_out, int out_size, void* d_ws, size_t ws_size,
                              hipStream_t stream) {
  const float* X = (const float*)d_in[0];
  unsigned short* ws = (unsigned short*)d_ws;
  unsigned short* Xb = ws + OFF_XB;
  unsigned short* Wb = ws + OFF_WB;
  unsigned short* QK = ws + OFF_QK;
  unsigned short* Vt = ws + OFF_VT;

  // scale = 1/sqrt(Dh) * log2(e), folded into Wq so scores come out in exp2 domain
  const float QSCALE = 0.125f * 1.44269504088896f;

  cvt_kernel<<<3072, 256, 0, stream>>>(X, Xb, 786432, 1.0f);
  wcvt_kernel<<<2880, 256, 0, stream>>>((const float*)d_in[1], (const float*)d_in[2],
                                        (const float*)d_in[3], (const float*)d_in[4],
                                        (const float*)d_in[5], Wb, QSCALE);

  proj_kernel<<<dim3(6, 5, 32), 256, 0, stream>>>(Xb, Wb, QK, Vt);
  attn_kernel<<<dim3(32, 12, 2), 256, 0, stream>>>(QK, Vt, (float*)d_out);
}

// Round 10
// 183.528 us; speedup vs baseline: 1.1245x; 1.0275x over previous
//
#include <hip/hip_runtime.h>
#include <cstdint>

typedef short bf16x8 __attribute__((ext_vector_type(8)));
typedef float f32x4 __attribute__((ext_vector_type(4)));

#define MFMA16(a, b, c) __builtin_amdgcn_mfma_f32_16x16x32_bf16((a), (b), (c), 0, 0, 0)

// async global->LDS DMA, 16B per lane. LDS dest is wave-uniform base + lane*16.
__device__ __forceinline__ void gl16(const unsigned short* g, unsigned short* l) {
  __builtin_amdgcn_global_load_lds(
      (const __attribute__((address_space(1))) unsigned int*)g,
      (__attribute__((address_space(3))) unsigned int*)l, 16, 0, 0);
}

__device__ __forceinline__ unsigned short f2b(float f) {
  union { float f; unsigned int u; } x; x.f = f;
  unsigned int r = x.u + 0x7fffu + ((x.u >> 16) & 1u);
  return (unsigned short)(r >> 16);
}

// fast pack two fp32 -> packed bf16x2 (round half-up; fine for probs in [1,16])
__device__ __forceinline__ unsigned int pack2(float lo, float hi) {
  union { float f; unsigned int u; } a, b;
  a.f = lo; b.f = hi;
  return ((a.u + 0x8000u) >> 16) | ((b.u + 0x8000u) & 0xffff0000u);
}

#define NB 2
#define NS 2048
#define ND 768
#define NH 12
#define DHD 64
#define MTOK 4096  // NB*NS

// ws element offsets (ushort/bf16 elements)
#define OFF_XB 0
#define OFF_WB 3145728   // 5 x 589824 converted weights
#define OFF_QK 6094848   // 4 x 3145728 : Qr,Qi,Kr,Ki  [4096][768]
#define OFF_VT 18677760  // Vt [2][12][64][2048]

__global__ void cvt_kernel(const float* __restrict__ src,
                           unsigned short* __restrict__ dst, int n4, float scale) {
  int i = blockIdx.x * blockDim.x + threadIdx.x;
  if (i >= n4) return;
  float4 v = ((const float4*)src)[i];
  ushort4 o;
  o.x = f2b(v.x * scale); o.y = f2b(v.y * scale);
  o.z = f2b(v.z * scale); o.w = f2b(v.w * scale);
  ((ushort4*)dst)[i] = o;
}

// all 5 weight matrices in one launch
__global__ void wcvt_kernel(const float* __restrict__ s0, const float* __restrict__ s1,
                            const float* __restrict__ s2, const float* __restrict__ s3,
                            const float* __restrict__ s4, unsigned short* __restrict__ dst,
                            float qs) {
  const int bz = blockIdx.x / 576;           // 576 blocks per weight (147456/256)
  const int i = (blockIdx.x % 576) * 256 + threadIdx.x;
  const float* src = bz == 0 ? s0 : bz == 1 ? s1 : bz == 2 ? s2 : bz == 3 ? s3 : s4;
  const float scale = bz < 2 ? qs : 1.0f;    // Wqr, Wqi carry the exp2-domain scale
  float4 v = ((const float4*)src)[i];
  ushort4 o;
  o.x = f2b(v.x * scale); o.y = f2b(v.y * scale);
  o.z = f2b(v.z * scale); o.w = f2b(v.w * scale);
  ((ushort4*)(dst + bz * 589824))[i] = o;
}

// out = X @ W^T for 5 weights (z). z<4 -> row-major bf16 [4096][768];
// z==4 -> V transposed per head: Vt[b][h][dh][s].
//
// 256x256 tile, BK=64, 512 threads / 8 waves (2m x 4n), 2-phase dbuf.
// Rationale (rounds 3-9): proj was schedule-invariant at ~83 us because each
// 128^2 K-step has only ~154 MFMA-cy/wave against a fixed stage+drain+barrier
// cost (m233: ~72% of a 2-phase step). 256^2 gives 4x MFMA per barrier, 2x
// less staged traffic (184 vs 368 MB), 2x FLOP/staged-byte. LDS = 128 KB
// (A dbuf 64K + B dbuf 64K), 1 block/CU, grid 240 = 8 XCDs x 30 (bijective).
// Swizzle unchanged: LDS[r][chunk] = G[r][chunk ^ (r&7)], read fo = ((ks*4+quad)^c7)*8.
// Epilogue: reuse staging LDS as T[128][264] in two halves, coalesced writes.
__global__ __launch_bounds__(512) void proj_kernel(
    const unsigned short* __restrict__ Xb, const unsigned short* __restrict__ Wb,
    unsigned short* __restrict__ QK, unsigned short* __restrict__ Vt) {
  __shared__ __align__(16) unsigned short S[65536];  // 128 KB
  // A buffers: S[0], S[16384]; B buffers: S[32768], S[49152] (ushort offsets)

  const int lin = blockIdx.x;
  const int sb = (lin & 7) * 30 + (lin >> 3);  // XCD-chunked, 240 = 8*30
  const int z = sb / 48;
  const int rem = sb % 48;
  const int m0 = (rem / 3) * 256;
  const int n0 = (rem % 3) * 256;

  const unsigned short* Wz = Wb + z * 589824;
  const int tid = threadIdx.x;
  const int lane = tid & 63;
  const int w = tid >> 6;                     // 8 waves
  const int wm = (w >> 2) * 128;              // 2 m-halves
  const int wn = (w & 3) * 64;                // 4 n-quarters
  const int col = lane & 15, quad = lane >> 4;
  const int c7 = col & 7;

  // staging: wave w covers rows {w*8+lr + i*64, i=0..3} of each 256x64 tile
  const int lr = lane >> 3;                   // row within 8-row group
  const int lc = (lane & 7) ^ (lr & 7);       // pre-swizzled source chunk
  const unsigned short* gX = Xb + (m0 + w * 8 + lr) * ND + lc * 8;
  const unsigned short* gW = Wz + (n0 + w * 8 + lr) * ND + lc * 8;
  const int stg = (w * 8) * 64;               // wave dest base within a buffer

  f32x4 acc[8][4] = {};

  // prologue: stage K-step 0 into buf 0
#pragma unroll
  for (int i = 0; i < 4; i++) {
    gl16(gX + i * (64 * ND), S + stg + i * 4096);
    gl16(gW + i * (64 * ND), S + 32768 + stg + i * 4096);
  }
  __syncthreads();  // drain: buf0 visible

  int cur = 0;
  for (int kk = 0; kk < 12; kk++) {
    if (kk < 11) {  // issue next-step loads BEFORE compute (hidden under MFMAs)
      const int k0n = (kk + 1) * 64;
      unsigned short* dA = S + ((cur ^ 1) * 16384) + stg;
      unsigned short* dB = S + 32768 + ((cur ^ 1) * 16384) + stg;
#pragma unroll
      for (int i = 0; i < 4; i++) {
        gl16(gX + i * (64 * ND) + k0n, dA + i * 4096);
        gl16(gW + i * (64 * ND) + k0n, dB + i * 4096);
      }
    }
    const unsigned short* Ac = S + cur * 16384;
    const unsigned short* Bc = S + 32768 + cur * 16384;
#pragma unroll
    for (int ks = 0; ks < 2; ks++) {
      const int fo = (((ks * 4 + quad) ^ c7) * 8);
      bf16x8 af[8], bw[4];
#pragma unroll
      for (int t = 0; t < 8; t++)
        af[t] = *(const bf16x8*)(Ac + (wm + t * 16 + col) * 64 + fo);
#pragma unroll
      for (int u = 0; u < 4; u++)
        bw[u] = *(const bf16x8*)(Bc + (wn + u * 16 + col) * 64 + fo);
#pragma unroll
      for (int mt = 0; mt < 8; mt++)
#pragma unroll
        for (int nt = 0; nt < 4; nt++)
          acc[mt][nt] = MFMA16(af[mt], bw[nt], acc[mt][nt]);
    }
    __syncthreads();  // drains vmcnt(0): next buf ready; cur safe to overwrite
    cur ^= 1;
  }

  // ---- epilogue: LDS-staged coalesced writeout, T[128][264], two halves ----
  unsigned short* T = S;

  if (z < 4) {
    unsigned short* out = QK + z * (MTOK * ND);
    const int wrow = w >> 2;
#pragma unroll
    for (int half = 0; half < 2; half++) {
      __syncthreads();
      if (wrow == half) {
#pragma unroll
        for (int mt = 0; mt < 8; mt++) {
          int rl = mt * 16 + quad * 4;  // local row within half
#pragma unroll
          for (int nt = 0; nt < 4; nt++) {
            int cl = wn + nt * 16 + col;
#pragma unroll
            for (int r = 0; r < 4; r++) T[(rl + r) * 264 + cl] = f2b(acc[mt][nt][r]);
          }
        }
      }
      __syncthreads();
#pragma unroll
      for (int p = 0; p < 8; p++) {
        int ci = p * 512 + tid;
        int row = ci >> 5;
        int c8 = (ci & 31) * 8;
        uint4 v = *(const uint4*)(T + row * 264 + c8);
        *(uint4*)(out + (m0 + half * 128 + row) * ND + n0 + c8) = v;
      }
    }
  } else {
    // Vt transpose: T[dh_local][s_local]; halves over the 256 output cols
    const int b = m0 >> 11;
    const int s_base = m0 & 2047;
    const int wcolh = (w & 3) >> 1;
#pragma unroll
    for (int half = 0; half < 2; half++) {
      __syncthreads();
      if (wcolh == half) {
        int clb = wn - half * 128;  // 0 or 64 for writer waves
#pragma unroll
        for (int mt = 0; mt < 8; mt++) {
          int rl = wm + mt * 16 + quad * 4;  // token index 0..255 (mult of 4)
#pragma unroll
          for (int nt = 0; nt < 4; nt++) {
            int cl = clb + nt * 16 + col;    // dh-local within half
            ushort4 pk;
            pk.x = f2b(acc[mt][nt][0]);
            pk.y = f2b(acc[mt][nt][1]);
            pk.z = f2b(acc[mt][nt][2]);
            pk.w = f2b(acc[mt][nt][3]);
            *(ushort4*)(T + cl * 264 + rl) = pk;
          }
        }
      }
      __syncthreads();
#pragma unroll
      for (int p = 0; p < 8; p++) {
        int ci = p * 512 + tid;
        int dhl = ci >> 5;
        int s8 = (ci & 31) * 8;
        int c = n0 + half * 128 + dhl;
        int h = c >> 6, dh = c & 63;
        uint4 v = *(const uint4*)(T + dhl * 264 + s8);
        *(uint4*)(Vt + ((b * NH + h) * DHD + dh) * NS + s_base + s8) = v;
      }
    }
  }
}

// Flash attention, scores transposed (S^T = K Q^T), complex magnitude variant.
// ROUND-5/9 VERSION (best measured 92.7 us): V-only double-buffer, Ps in LDS,
// K/Ki staged at mid barrier (covered by PV), V(t+1) into alt buffer.
// Load scheduling proven ~invariant (r3/r5/r8 all ~95); this is the cheapest.
// XCD-chunked swizzle keeps K/V panels resident in one XCD's L2.
__global__ __launch_bounds__(256) void attn_kernel(
    const unsigned short* __restrict__ QK, const unsigned short* __restrict__ Vt,
    float* __restrict__ outp) {
  __shared__ __align__(16) unsigned short Krs[4096];
  __shared__ __align__(16) unsigned short Kis[4096];
  __shared__ __align__(16) unsigned short Vts[8192];  // [2][64][64] double-buffered
  __shared__ __align__(16) unsigned short Ps[4096];

  const int lin = blockIdx.x + 32 * (blockIdx.y + 12 * blockIdx.z);
  const int sb = (lin & 7) * 96 + (lin >> 3);
  const int qt = sb & 31;
  const int h = (sb >> 5) % 12;
  const int b = sb / 384;
  const int tid = threadIdx.x, lane = tid & 63, w = tid >> 6;
  const int col = lane & 15, quad = lane >> 4;
  const int c7 = col & 7;
  const int jb = quad ^ c7;
  const int f0 = jb * 8, f1 = (jb ^ 4) * 8;  // swizzled fragment offsets (ushorts)

  const unsigned short* Qr = QK;
  const unsigned short* Qi = QK + MTOK * ND;
  const unsigned short* Krp = QK + 2 * MTOK * ND;
  const unsigned short* Kip = QK + 3 * MTOK * ND;

  const int q_tok = b * NS + qt * 64 + w * 16 + col;
  const int qoff = q_tok * ND + h * DHD;

  // Q as B-fragments: B[k=d][n=q], lane holds 8 consecutive d at its q.
  bf16x8 qrf[2], qif[2], qrn[2];
#pragma unroll
  for (int kk = 0; kk < 2; kk++) {
    qrf[kk] = *(const bf16x8*)(Qr + qoff + kk * 32 + quad * 8);
    qif[kk] = *(const bf16x8*)(Qi + qoff + kk * 32 + quad * 8);
    qrn[kk] = qrf[kk] ^ (short)0x8000;  // -Qr (bf16 sign flip)
  }

  // staging: wave w stages rows [w*8, w*8+8) and [32+w*8, ...) of each array.
  const int lr = lane >> 3;
  const int lc = (lane & 7) ^ (lr & 7);
  const unsigned short* gKr = Krp + (b * NS + w * 8 + lr) * ND + h * DHD + lc * 8;
  const unsigned short* gKi = Kip + (b * NS + w * 8 + lr) * ND + h * DHD + lc * 8;
  const unsigned short* gV = Vt + (b * NH + h) * (DHD * NS) + (w * 8 + lr) * NS + lc * 8;
  const int st = (w * 8) * 64;  // wave-uniform LDS base offset within a buffer

  unsigned short* PsW = Ps + w * 1024;

  f32x4 o[4] = {};  // O^T tiles: rows d = dt*16+quad*4+r, col q
  float lrow = 0.f;

  // prologue: stage tile 0 (K/Ki single buffer; V into buf 0)
  gl16(gKr, Krs + st);
  gl16(gKr + 32 * ND, Krs + st + 2048);
  gl16(gKi, Kis + st);
  gl16(gKi + 32 * ND, Kis + st + 2048);
  gl16(gV, Vts + st);
  gl16(gV + 32 * NS, Vts + st + 2048);
  gKr += 64 * ND;
  gKi += 64 * ND;
  gV += 64;

  int vb = 0;
  for (int kt = 0; kt < 32; kt++) {
    __syncthreads();  // drains vmcnt(0): tile kt's K/Ki/V landed

    // ---- QK^T phase (reads Krs/Kis; writes P to LDS) ----
#pragma unroll
    for (int mt = 0; mt < 4; mt++) {
      f32x4 sr = {}, si = {};
      const int rowb = (mt * 16 + col) * 64;
      bf16x8 kr0 = *(const bf16x8*)(Krs + rowb + f0);
      bf16x8 ki0 = *(const bf16x8*)(Kis + rowb + f0);
      bf16x8 kr1 = *(const bf16x8*)(Krs + rowb + f1);
      bf16x8 ki1 = *(const bf16x8*)(Kis + rowb + f1);
      sr = MFMA16(kr0, qrf[0], sr);
      sr = MFMA16(ki0, qif[0], sr);
      si = MFMA16(kr0, qif[0], si);
      si = MFMA16(ki0, qrn[0], si);
      sr = MFMA16(kr1, qrf[1], sr);
      sr = MFMA16(ki1, qif[1], sr);
      si = MFMA16(kr1, qif[1], si);
      si = MFMA16(ki1, qrn[1], si);

      float e0, e1, e2, e3;
      {
        float m0f = __builtin_amdgcn_sqrtf(sr[0] * sr[0] + si[0] * si[0]);
        float m1f = __builtin_amdgcn_sqrtf(sr[1] * sr[1] + si[1] * si[1]);
        float m2f = __builtin_amdgcn_sqrtf(sr[2] * sr[2] + si[2] * si[2]);
        float m3f = __builtin_amdgcn_sqrtf(sr[3] * sr[3] + si[3] * si[3]);
        e0 = __builtin_amdgcn_exp2f(m0f);
        e1 = __builtin_amdgcn_exp2f(m1f);
        e2 = __builtin_amdgcn_exp2f(m2f);
        e3 = __builtin_amdgcn_exp2f(m3f);
      }
      lrow += (e0 + e1) + (e2 + e3);
      uint2 pk;
      pk.x = pack2(e0, e1);
      pk.y = pack2(e2, e3);
      *(uint2*)(PsW + col * 64 + (((mt * 2 + (quad >> 1)) ^ c7) * 8) + (quad & 1) * 4) = pk;
    }

    __syncthreads();  // all waves done reading Krs/Kis (K dead); lgkm drained -> Ps visible

    // ---- stage tile kt+1 NOW: latency hides under the PV phase below ----
    if (kt < 31) {
      const int nb = (vb ^ 1) * 4096;
      gl16(gKr, Krs + st);
      gl16(gKr + 32 * ND, Krs + st + 2048);
      gl16(gKi, Kis + st);
      gl16(gKi + 32 * ND, Kis + st + 2048);
      gl16(gV, Vts + nb + st);
      gl16(gV + 32 * NS, Vts + nb + st + 2048);
      gKr += 64 * ND;
      gKi += 64 * ND;
      gV += 64;
    }

    // ---- PV phase: O^T += V^T · P^T (reads Vts[vb], Ps) ----
    const unsigned short* Vc = Vts + vb * 4096;
    bf16x8 pb0 = *(const bf16x8*)(PsW + col * 64 + f0);
    bf16x8 pb1 = *(const bf16x8*)(PsW + col * 64 + f1);
#pragma unroll
    for (int dt = 0; dt < 4; dt++) {
      const int rowv = (dt * 16 + col) * 64;
      bf16x8 va0 = *(const bf16x8*)(Vc + rowv + f0);
      bf16x8 va1 = *(const bf16x8*)(Vc + rowv + f1);
      o[dt] = MFMA16(va0, pb0, o[dt]);
      o[dt] = MFMA16(va1, pb1, o[dt]);
    }
    vb ^= 1;
  }

  lrow += __shfl_xor(lrow, 16);
  lrow += __shfl_xor(lrow, 32);
  float inv_l = 1.0f / lrow;
  float* op = outp + (size_t)q_tok * ND + h * DHD;
#pragma unroll
  for (int dt = 0; dt < 4; dt++) {
    float4 v;
    v.x = o[dt][0] * inv_l;
    v.y = o[dt][1] * inv_l;
    v.z = o[dt][2] * inv_l;
    v.w = o[dt][3] * inv_l;
    *(float4*)(op + dt * 16 + quad * 4) = v;
  }
}

extern "C" void kernel_launch(void* const* d_in, const int* in_sizes, int n_in,
                              void* d_out, int out_size, void* d_ws, size_t ws_size,
                              hipStream_t stream) {
  const float* X = (const float*)d_in[0];
  unsigned short* ws = (unsigned short*)d_ws;
  unsigned short* Xb = ws + OFF_XB;
  unsigned short* Wb = ws + OFF_WB;
  unsigned short* QK = ws + OFF_QK;
  unsigned short* Vt = ws + OFF_VT;

  // scale = 1/sqrt(Dh) * log2(e), folded into Wq so scores come out in exp2 domain
  const float QSCALE = 0.125f * 1.44269504088896f;

  cvt_kernel<<<3072, 256, 0, stream>>>(X, Xb, 786432, 1.0f);
  wcvt_kernel<<<2880, 256, 0, stream>>>((const float*)d_in[1], (const float*)d_in[2],
                                        (const float*)d_in[3], (const float*)d_in[4],
                                        (const float*)d_in[5], Wb, QSCALE);

  proj_kernel<<<240, 512, 0, stream>>>(Xb, Wb, QK, Vt);
  attn_kernel<<<dim3(32, 12, 2), 256, 0, stream>>>(QK, Vt, (float*)d_out);
}